// Round 7
// baseline (56.814 us; speedup 1.0000x reference)
//
#include <hip/hip_runtime.h>
#include <stdint.h>

#define NBATCH 4
#define NS 2048
#define ND 1024
#define NK 64
#define QSCALE 0.18033688011112042f  // 0.125 * log2(e), folded into Q

typedef __attribute__((ext_vector_type(4))) float f32x4;
typedef __attribute__((ext_vector_type(16))) float f32x16;
typedef __attribute__((ext_vector_type(8))) short bf16x8;
typedef unsigned short u16;
typedef unsigned int u32;
typedef unsigned long long u64;

__device__ __forceinline__ u16 f2bf(float f) {
  union { float f; u32 u; } v; v.f = f;
  u32 u = v.u;
  u += 0x7FFFu + ((u >> 16) & 1u);   // RNE
  return (u16)(u >> 16);
}

__device__ __forceinline__ u32 pk2(float lo, float hi) {
  u32 r;
  asm("v_cvt_pk_bf16_f32 %0, %1, %2" : "=v"(r) : "v"(lo), "v"(hi));
  return r;
}

// ---------------------------------------------------------------------------
// Kernel 0: W ([1024][64] f32, x3) -> Wt [192][1024] bf16 (transposed).
// ---------------------------------------------------------------------------
__global__ __launch_bounds__(256) void wtrans_kernel(
    const float* __restrict__ Wq, const float* __restrict__ Wk,
    const float* __restrict__ Wv, u16* __restrict__ Wt) {
  __shared__ float tile[64][65];
  int blk = blockIdx.x;            // 48 blocks: 3 matrices x 16 d-tiles
  int m = blk >> 4, dt = blk & 15;
  const float* W = (m == 0) ? Wq : (m == 1) ? Wk : Wv;
  int d0 = dt * 64;
  int t = threadIdx.x;
#pragma unroll
  for (int i = 0; i < 16; i++) {
    int idx = t + 256 * i;
    int dd = idx >> 6, c = idx & 63;
    tile[dd][c] = W[(d0 + dd) * 64 + c];
  }
  __syncthreads();
#pragma unroll
  for (int i = 0; i < 16; i++) {
    int idx = t + 256 * i;
    int c = idx >> 6, dd = idx & 63;
    Wt[(m * 64 + c) * 1024 + d0 + dd] = f2bf(tile[dd][c]);
  }
}

// ---------------------------------------------------------------------------
// Kernel 1: QKV projection, LDS-staged (unchanged from R5 — verified).
// ---------------------------------------------------------------------------
__global__ __launch_bounds__(512) void qkv_kernel(
    const float* __restrict__ x, const u16* __restrict__ Wt,
    const float* __restrict__ Bq, const float* __restrict__ Bk,
    const float* __restrict__ Bv, u16* __restrict__ Qf,
    u16* __restrict__ Kf, u16* __restrict__ Vf) {
  __shared__ __attribute__((aligned(16))) char lds[57344];
  char* ldsx = lds;              // [2][4096]  x-tile  (32 rows x 64 k bf16)
  char* ldsw = lds + 8192;       // [2][24576] Wt-tile (192 cols x 64 k bf16)

  int tid = threadIdx.x;
  int w = tid >> 6, lane = tid & 63;
  int g = lane >> 4, c = lane & 15;
  int rh = w & 1, cq = w >> 1;

  int xrow = tid >> 4;                    // 0..31
  int xp4  = tid & 15;                    // 16B piece within 256B f32 row
  const float* xsrc = x + ((long)blockIdx.x * 32 + xrow) * ND + xp4 * 4;
  int xwoff = xrow * 128 + ((xp4 * 8) ^ ((xrow & 7) << 4));

  int wrow = tid >> 3;                    // 0..63 within each 64-col group
  int wslot = tid & 7;                    // 16B piece within 128B bf16 row
  const u16* wsrc0 = Wt + (long)wrow * ND + wslot * 8;
  const u16* wsrc1 = Wt + (long)(64 + wrow) * ND + wslot * 8;
  const u16* wsrc2 = Wt + (long)(128 + wrow) * ND + wslot * 8;
  int wswz = (wrow & 7) << 4;
  int wwoff0 = wrow * 128 + ((wslot * 16) ^ wswz);
  int wwoff1 = (64 + wrow) * 128 + ((wslot * 16) ^ wswz);
  int wwoff2 = (128 + wrow) * 128 + ((wslot * 16) ^ wswz);

  int rowa = rh * 16 + c;
  int aswz = (rowa & 7) << 4;
  int aoff0 = rowa * 128 + ((g * 16) ^ aswz);
  int aoff1 = rowa * 128 + ((64 + g * 16) ^ aswz);
  int boff00, boff01, boff10, boff11, boff20, boff21;
  {
    int col = cq * 48 + c;
    int bz = (col & 7) << 4;
    boff00 = col * 128 + ((g * 16) ^ bz);
    boff01 = col * 128 + ((64 + g * 16) ^ bz);
    col += 16; bz = (col & 7) << 4;
    boff10 = col * 128 + ((g * 16) ^ bz);
    boff11 = col * 128 + ((64 + g * 16) ^ bz);
    col += 16; bz = (col & 7) << 4;
    boff20 = col * 128 + ((g * 16) ^ bz);
    boff21 = col * 128 + ((64 + g * 16) ^ bz);
  }

  f32x4 acc[3];
#pragma unroll
  for (int tt = 0; tt < 3; tt++) acc[tt] = (f32x4){0.f, 0.f, 0.f, 0.f};

  f32x4 xst;
  bf16x8 wst0, wst1, wst2;

#define LOADS(T) do {                                   \
    xst  = *(const f32x4*)(xsrc + (T) * 64);            \
    wst0 = *(const bf16x8*)(wsrc0 + (T) * 64);          \
    wst1 = *(const bf16x8*)(wsrc1 + (T) * 64);          \
    wst2 = *(const bf16x8*)(wsrc2 + (T) * 64);          \
  } while (0)

#define WRITES(NB) do {                                 \
    u32 lo_ = pk2(xst[0], xst[1]);                      \
    u32 hi_ = pk2(xst[2], xst[3]);                      \
    *(u64*)(ldsx + (NB) * 4096 + xwoff) = ((u64)hi_ << 32) | lo_; \
    *(bf16x8*)(ldsw + (NB) * 24576 + wwoff0) = wst0;    \
    *(bf16x8*)(ldsw + (NB) * 24576 + wwoff1) = wst1;    \
    *(bf16x8*)(ldsw + (NB) * 24576 + wwoff2) = wst2;    \
  } while (0)

#define COMPUTE(B) do {                                 \
    const char* xb_ = ldsx + (B) * 4096;                \
    const char* wb_ = ldsw + (B) * 24576;               \
    bf16x8 a0_ = *(const bf16x8*)(xb_ + aoff0);         \
    bf16x8 a1_ = *(const bf16x8*)(xb_ + aoff1);         \
    acc[0] = __builtin_amdgcn_mfma_f32_16x16x32_bf16(a0_, *(const bf16x8*)(wb_ + boff00), acc[0], 0, 0, 0); \
    acc[0] = __builtin_amdgcn_mfma_f32_16x16x32_bf16(a1_, *(const bf16x8*)(wb_ + boff01), acc[0], 0, 0, 0); \
    acc[1] = __builtin_amdgcn_mfma_f32_16x16x32_bf16(a0_, *(const bf16x8*)(wb_ + boff10), acc[1], 0, 0, 0); \
    acc[1] = __builtin_amdgcn_mfma_f32_16x16x32_bf16(a1_, *(const bf16x8*)(wb_ + boff11), acc[1], 0, 0, 0); \
    acc[2] = __builtin_amdgcn_mfma_f32_16x16x32_bf16(a0_, *(const bf16x8*)(wb_ + boff20), acc[2], 0, 0, 0); \
    acc[2] = __builtin_amdgcn_mfma_f32_16x16x32_bf16(a1_, *(const bf16x8*)(wb_ + boff21), acc[2], 0, 0, 0); \
  } while (0)

  LOADS(0);
  WRITES(0);
  __syncthreads();
#pragma unroll
  for (int t = 0; t < 16; t++) {
    if (t < 15) LOADS(t + 1);
    __builtin_amdgcn_sched_barrier(0);
    COMPUTE(t & 1);
    if (t < 15) WRITES((t + 1) & 1);
    __syncthreads();
  }
#undef LOADS
#undef WRITES
#undef COMPUTE

  // epilogue: bias + write in MFMA-fragment order
  long r0 = (long)blockIdx.x * 32 + rh * 16 + 4 * g;
#pragma unroll
  for (int tt = 0; tt < 3; tt++) {
    int colg = cq * 48 + tt * 16 + c;
    int mtx = colg >> 6;                 // 0=Q 1=K 2=V (wave-uniform)
    int col = colg & 63;
    const float* Bias = (mtx == 0) ? Bq : (mtx == 1) ? Bk : Bv;
    u16* Out = (mtx == 0) ? Qf : (mtx == 1) ? Kf : Vf;
#pragma unroll
    for (int j = 0; j < 4; j++) {
      long r = r0 + j;
      int srow = (int)(r & (NS - 1));
      int bb = (int)(r >> 11);
      float v = acc[tt][j] + Bias[srow * NK + col];
      if (mtx == 0) v *= QSCALE;
      long addr;
      if (mtx < 2) {
        addr = (((long)bb * 64 + (srow >> 5)) * 4 + (col >> 4)) * 512
             + (long)((srow & 31) + ((col >> 3) & 1) * 32) * 8 + (col & 7);
      } else {
        addr = ((((long)bb * 2 + ((col >> 5) & 1)) * 32 + (srow >> 6)) * 4 + ((srow >> 4) & 3)) * 512
             + (long)((col & 31) + ((srow >> 3) & 1) * 32) * 8 + (srow & 7);
      }
      Out[addr] = f2bf(v);
    }
  }
}

// ---------------------------------------------------------------------------
// Kernel 2: flash attention (R5 structure, verified) + waves_per_eu(2,2).
// The wave needs ~216 VGPRs; without the clamp hipcc's occupancy-targeting
// allocator spills f32x16 state to scratch in the inner loop (R2/R3 disease,
// suspected cause of attn ~25us vs ~5us model). Grid runs exactly 2 waves/
// SIMD, so (2,2) grants the full 256-VGPR half-file. Launched 3x in
// kernel_launch (idempotent) for per-kernel time attribution.
// ---------------------------------------------------------------------------
__device__ __forceinline__ bf16x8 pack8(float p0, float p1, float p2, float p3,
                                        float p4, float p5, float p6, float p7,
                                        int hi) {
  u32 A = pk2(p0, p1), B = pk2(p2, p3), C = pk2(p4, p5), D = pk2(p6, p7);
  u32 sA = (u32)__shfl_xor((int)A, 32);
  u32 sB = (u32)__shfl_xor((int)B, 32);
  u32 sC = (u32)__shfl_xor((int)C, 32);
  u32 sD = (u32)__shfl_xor((int)D, 32);
  union { u32 w[4]; bf16x8 v; } u;
  u.w[0] = hi ? sC : A;
  u.w[1] = hi ? sD : B;
  u.w[2] = hi ? C : sA;
  u.w[3] = hi ? D : sB;
  return u.v;
}

__global__ __launch_bounds__(512) __attribute__((amdgpu_waves_per_eu(2, 2)))
void attn_kernel(
    const u16* __restrict__ Qf, const u16* __restrict__ Kf,
    const u16* __restrict__ Vf, float* __restrict__ out) {
  __shared__ float Ol[8][32][64];
  __shared__ float Ll[8][32];
  int w = threadIdx.x >> 6, lane = threadIdx.x & 63;
  int q = lane & 31, hi = lane >> 5;
  int bid = blockIdx.x;
  int b = (bid & 7) >> 1;                      // batch b on XCDs {2b,2b+1}
  int qt = ((bid >> 3) << 1) | (bid & 1);
  long qglob = (long)b * NS + qt * 32;

  bf16x8 qf[4];
  {
    const u16* qp = Qf + ((long)b * 64 + qt) * 2048 + lane * 8;
#pragma unroll
    for (int kk = 0; kk < 4; kk++) qf[kk] = *(const bf16x8*)(qp + kk * 512);
  }
  // K chunks: (b*64 + w*8 + t*2 + {0,1}) * 2048 + kk*512 + lane*8
  const u16* kcp = Kf + ((long)b * 64 + w * 8) * 2048 + lane * 8;
  // V chunks: ((b*2+half)*32 + w*4 + t) * 2048 + i*512 + lane*8
  const u16* vcp0 = Vf + ((long)b * 64 + w * 4) * 2048 + lane * 8;
  const u16* vcp1 = Vf + ((long)(b * 2 + 1) * 32 + w * 4) * 2048 + lane * 8;

  f32x16 o0, o1;
#pragma unroll
  for (int r = 0; r < 16; r++) { o0[r] = 0.f; o1[r] = 0.f; }
  float lacc[4] = {0.f, 0.f, 0.f, 0.f};

  bf16x8 kA0[4], kA1[4], kB0[4], kB1[4];
#pragma unroll
  for (int kk = 0; kk < 4; kk++) {             // prologue: K frags for t=0
    kA0[kk] = *(const bf16x8*)(kcp + kk * 512);
    kA1[kk] = *(const bf16x8*)(kcp + 2048 + kk * 512);
  }

#define ATTN_STEP(T, KC0, KC1, KN0, KN1)                                      \
  do {                                                                        \
    int t_ = (T);                                                             \
    bf16x8 vf0[4], vf1[4];                                                    \
    _Pragma("unroll") for (int i = 0; i < 4; i++) {                           \
      vf0[i] = *(const bf16x8*)(vcp0 + t_ * 2048 + i * 512);                  \
      vf1[i] = *(const bf16x8*)(vcp1 + t_ * 2048 + i * 512);                  \
    }                                                                         \
    if (t_ + 1 < 4) {                                                         \
      const u16* kn_ = kcp + (long)(t_ + 1) * 4096;                           \
      _Pragma("unroll") for (int i = 0; i < 4; i++) {                         \
        KN0[i] = *(const bf16x8*)(kn_ + i * 512);                             \
        KN1[i] = *(const bf16x8*)(kn_ + 2048 + i * 512);                      \
      }                                                                       \
    }                                                                         \
    __builtin_amdgcn_sched_barrier(0);                                        \
    f32x16 s0, s1;                                                            \
    _Pragma("unroll") for (int r = 0; r < 16; r++) { s0[r] = 0.f; s1[r] = 0.f; } \
    _Pragma("unroll") for (int i = 0; i < 4; i++)                             \
      s0 = __builtin_amdgcn_mfma_f32_32x32x16_bf16(KC0[i], qf[i], s0, 0, 0, 0); \
    _Pragma("unroll") for (int i = 0; i < 4; i++)                             \
      s1 = __builtin_amdgcn_mfma_f32_32x32x16_bf16(KC1[i], qf[i], s1, 0, 0, 0); \
    _Pragma("unroll") for (int r = 0; r < 16; r++) {                          \
      s0[r] = exp2f(s0[r]); s1[r] = exp2f(s1[r]);                             \
      lacc[r & 3] += s0[r] + s1[r];                                           \
    }                                                                         \
    bf16x8 pa[4];                                                             \
    pa[0] = pack8(s0[0], s0[1], s0[2], s0[3], s0[4], s0[5], s0[6], s0[7], hi);   \
    pa[1] = pack8(s0[8], s0[9], s0[10], s0[11], s0[12], s0[13], s0[14], s0[15], hi); \
    pa[2] = pack8(s1[0], s1[1], s1[2], s1[3], s1[4], s1[5], s1[6], s1[7], hi);   \
    pa[3] = pack8(s1[8], s1[9], s1[10], s1[11], s1[12], s1[13], s1[14], s1[15], hi); \
    _Pragma("unroll") for (int i = 0; i < 4; i++) {                           \
      o0 = __builtin_amdgcn_mfma_f32_32x32x16_bf16(pa[i], vf0[i], o0, 0, 0, 0); \
      o1 = __builtin_amdgcn_mfma_f32_32x32x16_bf16(pa[i], vf1[i], o1, 0, 0, 0); \
    }                                                                         \
  } while (0)

  ATTN_STEP(0, kA0, kA1, kB0, kB1);
  ATTN_STEP(1, kB0, kB1, kA0, kA1);
  ATTN_STEP(2, kA0, kA1, kB0, kB1);
  ATTN_STEP(3, kB0, kB1, kA0, kA1);
#undef ATTN_STEP

  float lt = (lacc[0] + lacc[1]) + (lacc[2] + lacc[3]);
  lt += __shfl_xor(lt, 32);

  // stage per-wave partials (D row = (r&3)+8*(r>>2)+4*hi = q-row; col = k)
#pragma unroll
  for (int r = 0; r < 16; r++) {
    int qq = (r & 3) + 8 * (r >> 2) + 4 * hi;
    Ol[w][qq][q]      = o0[r];
    Ol[w][qq][q + 32] = o1[r];
  }
  if (hi == 0) Ll[w][q] = lt;
  __syncthreads();

  // tree reduce across waves: 4, 2, 1
#pragma unroll
  for (int rr = 4; rr >= 1; rr >>= 1) {
    if (w < rr) {
#pragma unroll
      for (int i = 0; i < 8; i++) {
        int idx = lane + i * 64;               // 0..511 over 2048 f32 (x4)
        f32x4* dst = (f32x4*)&Ol[w][idx >> 4][(idx & 15) * 4];
        const f32x4* src = (const f32x4*)&Ol[w + rr][idx >> 4][(idx & 15) * 4];
        *dst += *src;
      }
      if (lane < 32) Ll[w][lane] += Ll[w + rr][lane];
    }
    __syncthreads();
  }

  // normalize + store: 512 threads x 1 f32x4 = 32 rows x 64 cols
  {
    int idx = threadIdx.x;
    int row = idx >> 4, c4 = (idx & 15) * 4;
    float inv = 1.0f / Ll[0][row];
    f32x4 v = *(const f32x4*)&Ol[0][row][c4];
    f32x4 r;
#pragma unroll
    for (int i = 0; i < 4; i++) r[i] = v[i] * inv;
    *(f32x4*)&out[(qglob + row) * NK + c4] = r;
  }
}

// ---------------------------------------------------------------------------
extern "C" void kernel_launch(void* const* d_in, const int* in_sizes, int n_in,
                              void* d_out, int out_size, void* d_ws, size_t ws_size,
                              hipStream_t stream) {
  const float* x  = (const float*)d_in[0];
  const float* Wq = (const float*)d_in[1];
  const float* Bq = (const float*)d_in[2];
  const float* Wk = (const float*)d_in[3];
  const float* Bk = (const float*)d_in[4];
  const float* Wv = (const float*)d_in[5];
  const float* Bv = (const float*)d_in[6];
  float* out = (float*)d_out;

  char* ws = (char*)d_ws;
  u16* Wt = (u16*)ws;                         // 384 KB
  u16* Qf = (u16*)(ws + 393216);              // 1 MB, fragment order
  u16* Kf = (u16*)(ws + 1441792);             // 1 MB, fragment order
  u16* Vf = (u16*)(ws + 2490368);             // 1 MB, fragment order

  wtrans_kernel<<<dim3(48), dim3(256), 0, stream>>>(Wq, Wk, Wv, Wt);
  qkv_kernel<<<dim3(256), dim3(512), 0, stream>>>(x, Wt, Bq, Bk, Bv, Qf, Kf, Vf);
  // Attribution probe: attn is idempotent (reads Qf/Kf/Vf, writes out).
  // attn_us = (dur_total - base~9us) / 3.  Remove repeats next round.
  attn_kernel<<<dim3(256), dim3(512), 0, stream>>>(Qf, Kf, Vf, out);
  attn_kernel<<<dim3(256), dim3(512), 0, stream>>>(Qf, Kf, Vf, out);
  attn_kernel<<<dim3(256), dim3(512), 0, stream>>>(Qf, Kf, Vf, out);
}

// Round 8
// 31.571 us; speedup vs baseline: 1.7996x; 1.7996x over previous
//
#include <hip/hip_runtime.h>
#include <stdint.h>

#define NBATCH 4
#define NS 2048
#define ND 1024
#define NK 64
#define QSCALE 0.18033688011112042f  // 0.125 * log2(e), folded into Q

typedef __attribute__((ext_vector_type(4))) float f32x4;
typedef __attribute__((ext_vector_type(16))) float f32x16;
typedef __attribute__((ext_vector_type(8))) short bf16x8;
typedef unsigned short u16;
typedef unsigned int u32;
typedef unsigned long long u64;

__device__ __forceinline__ u16 f2bf(float f) {
  union { float f; u32 u; } v; v.f = f;
  u32 u = v.u;
  u += 0x7FFFu + ((u >> 16) & 1u);   // RNE
  return (u16)(u >> 16);
}

__device__ __forceinline__ u32 pk2(float lo, float hi) {
  u32 r;
  asm("v_cvt_pk_bf16_f32 %0, %1, %2" : "=v"(r) : "v"(lo), "v"(hi));
  return r;
}

__device__ __forceinline__ void gll16(const void* g, void* l) {
  __builtin_amdgcn_global_load_lds(
      (const __attribute__((address_space(1))) unsigned int*)g,
      (__attribute__((address_space(3))) unsigned int*)l, 16, 0, 0);
}

// ---------------------------------------------------------------------------
// Kernel 0: W ([1024][64] f32, x3) -> Wt [192][1024] bf16 (unchanged R5).
// ---------------------------------------------------------------------------
__global__ __launch_bounds__(256) void wtrans_kernel(
    const float* __restrict__ Wq, const float* __restrict__ Wk,
    const float* __restrict__ Wv, u16* __restrict__ Wt) {
  __shared__ float tile[64][65];
  int blk = blockIdx.x;            // 48 blocks: 3 matrices x 16 d-tiles
  int m = blk >> 4, dt = blk & 15;
  const float* W = (m == 0) ? Wq : (m == 1) ? Wk : Wv;
  int d0 = dt * 64;
  int t = threadIdx.x;
#pragma unroll
  for (int i = 0; i < 16; i++) {
    int idx = t + 256 * i;
    int dd = idx >> 6, c = idx & 63;
    tile[dd][c] = W[(d0 + dd) * 64 + c];
  }
  __syncthreads();
#pragma unroll
  for (int i = 0; i < 16; i++) {
    int idx = t + 256 * i;
    int c = idx >> 6, dd = idx & 63;
    Wt[(m * 64 + c) * 1024 + d0 + dd] = f2bf(tile[dd][c]);
  }
}

// ---------------------------------------------------------------------------
// Kernel 1: QKV projection v2.
// 256 blocks x 512 thr. global_load_lds(16B) staging, TRIPLE-buffered LDS,
// counted vmcnt(4) + raw s_barrier (loads for step t+2 in flight across 2
// steps ~= HBM latency). x staged as f32 (pre-swizzled global src, linear
// LDS dest, 32B-slot XOR), Wt bf16 (16B-piece XOR). Epilogue: acc -> LDS
// re-stage -> contiguous 16B/lane chunk writes (block owns 12 x 1KB chunks;
// kills the 2B-scatter RMW of R5-R7). Chunk layout identical to R5 (verified).
// ---------------------------------------------------------------------------
__global__ __launch_bounds__(512) void qkv_kernel(
    const float* __restrict__ x, const u16* __restrict__ Wt,
    const float* __restrict__ Bq, const float* __restrict__ Bk,
    const float* __restrict__ Bv, u16* __restrict__ Qf,
    u16* __restrict__ Kf, u16* __restrict__ Vf) {
  __shared__ __attribute__((aligned(16))) char lds[98304];
  char* ldsx = lds;              // 3 bufs x 8192 B  (32 rows x 64 f32)
  char* ldsw = lds + 24576;      // 3 bufs x 24576 B (192 rows x 64 bf16)

  int tid = threadIdx.x;
  int w = tid >> 6, lane = tid & 63;
  int g = lane >> 4, c = lane & 15;
  int rh = w & 1, cq = w >> 1;

  // ---- staging sources (per-lane, XOR-pre-swizzled) ----
  int xrow_l = 4 * w + (lane >> 4);                    // local row 0..31
  long xrow_g = (long)blockIdx.x * 32 + xrow_l;
  int xs32 = ((lane >> 1) & 7) ^ (xrow_l & 7);         // swizzled 32B slot
  const char* xg = (const char*)(x + xrow_g * ND) + xs32 * 32 + (lane & 1) * 16;

  int wr0 = 8 * w + (lane >> 3);                       // Wt rows, j=0/1/2
  const char* wg0 = (const char*)(Wt + (long)(wr0)       * ND) + (((lane & 7) ^ (wr0 & 7)) * 16);
  const char* wg1 = (const char*)(Wt + (long)(64 + wr0)  * ND) + (((lane & 7) ^ (wr0 & 7)) * 16);
  const char* wg2 = (const char*)(Wt + (long)(128 + wr0) * ND) + (((lane & 7) ^ (wr0 & 7)) * 16);
  int wd0 = (8 * w) * 128, wd1 = (64 + 8 * w) * 128, wd2 = (128 + 8 * w) * 128;

  // ---- compute-side offsets ----
  int rowa = rh * 16 + c;
  int axor = rowa & 7;
  int aoff0 = rowa * 256 + ((g ^ axor) * 32);          // kk=0
  int aoff1 = rowa * 256 + (((4 + g) ^ axor) * 32);    // kk=1
  int boff[3][2];
#pragma unroll
  for (int tt = 0; tt < 3; tt++) {
    int col = cq * 48 + tt * 16 + c;
#pragma unroll
    for (int kk = 0; kk < 2; kk++)
      boff[tt][kk] = col * 128 + (((kk * 4 + g) ^ (col & 7)) * 16);
  }

  f32x4 acc[3];
#pragma unroll
  for (int tt = 0; tt < 3; tt++) acc[tt] = (f32x4){0.f, 0.f, 0.f, 0.f};

#define STAGE(BUF, T) do {                                            \
    gll16(xg + (long)(T) * 256, ldsx + (BUF) * 8192 + w * 1024);      \
    gll16(wg0 + (T) * 128, ldsw + (BUF) * 24576 + wd0);               \
    gll16(wg1 + (T) * 128, ldsw + (BUF) * 24576 + wd1);               \
    gll16(wg2 + (T) * 128, ldsw + (BUF) * 24576 + wd2);               \
  } while (0)

#define COMPUTE(B) do {                                               \
    const char* xb_ = ldsx + (B) * 8192;                              \
    const char* wb_ = ldsw + (B) * 24576;                             \
    f32x4 p0_ = *(const f32x4*)(xb_ + aoff0);                         \
    f32x4 p1_ = *(const f32x4*)(xb_ + aoff0 + 16);                    \
    f32x4 p2_ = *(const f32x4*)(xb_ + aoff1);                         \
    f32x4 p3_ = *(const f32x4*)(xb_ + aoff1 + 16);                    \
    union { bf16x8 v; u32 w[4]; } af0, af1;                           \
    af0.w[0] = pk2(p0_[0], p0_[1]); af0.w[1] = pk2(p0_[2], p0_[3]);   \
    af0.w[2] = pk2(p1_[0], p1_[1]); af0.w[3] = pk2(p1_[2], p1_[3]);   \
    af1.w[0] = pk2(p2_[0], p2_[1]); af1.w[1] = pk2(p2_[2], p2_[3]);   \
    af1.w[2] = pk2(p3_[0], p3_[1]); af1.w[3] = pk2(p3_[2], p3_[3]);   \
    _Pragma("unroll")                                                 \
    for (int tt = 0; tt < 3; tt++) {                                  \
      bf16x8 b0_ = *(const bf16x8*)(wb_ + boff[tt][0]);               \
      bf16x8 b1_ = *(const bf16x8*)(wb_ + boff[tt][1]);               \
      acc[tt] = __builtin_amdgcn_mfma_f32_16x16x32_bf16(af0.v, b0_, acc[tt], 0, 0, 0); \
      acc[tt] = __builtin_amdgcn_mfma_f32_16x16x32_bf16(af1.v, b1_, acc[tt], 0, 0, 0); \
    }                                                                 \
  } while (0)

  STAGE(0, 0);
  STAGE(1, 1);
#pragma unroll
  for (int t = 0; t < 16; t++) {
    if (t < 15) asm volatile("s_waitcnt vmcnt(4)" ::: "memory");
    else        asm volatile("s_waitcnt vmcnt(0)" ::: "memory");
    __builtin_amdgcn_s_barrier();
    __builtin_amdgcn_sched_barrier(0);
    if (t + 2 < 16) STAGE((t + 2) % 3, t + 2);
    __builtin_amdgcn_sched_barrier(0);
    COMPUTE(t % 3);
  }
#undef STAGE
#undef COMPUTE

  // ---- epilogue: acc -> LDS chunks -> contiguous global writes ----
  __syncthreads();                       // all ds_reads of loop done
  u16* ep = (u16*)lds;                   // 12 chunks x 512 u16 = 12 KB
  int il = blockIdx.x & 63, bb = blockIdx.x >> 6;
#pragma unroll
  for (int tt = 0; tt < 3; tt++) {
    int colg = cq * 48 + tt * 16 + c;
    int mtx = colg >> 6;
    int col = colg & 63;
    const float* Bias = (mtx == 0) ? Bq : (mtx == 1) ? Bk : Bv;
#pragma unroll
    for (int j = 0; j < 4; j++) {
      int sl = rh * 16 + 4 * g + j;      // local row 0..31
      float v = acc[tt][j] + Bias[(il * 32 + sl) * NK + col];
      if (mtx == 0) v *= QSCALE;
      int chunk, off;
      if (mtx < 2) {
        chunk = mtx * 4 + (col >> 4);
        off = (sl + ((col >> 3) & 1) * 32) * 8 + (col & 7);
      } else {
        chunk = 8 + (col >> 5) * 2 + (sl >> 4);
        off = ((col & 31) + ((sl >> 3) & 1) * 32) * 8 + (sl & 7);
      }
      ep[chunk * 512 + off] = f2bf(v);
    }
  }
  __syncthreads();
  for (int t5 = tid; t5 < 768; t5 += 512) {
    int ch = t5 >> 6, pc = t5 & 63;
    bf16x8 val = *(const bf16x8*)(ep + ch * 512 + pc * 8);
    u16* dst;
    if (ch < 4)
      dst = Qf + (((long)bb * 64 + il) * 4 + ch) * 512 + pc * 8;
    else if (ch < 8)
      dst = Kf + (((long)bb * 64 + il) * 4 + (ch - 4)) * 512 + pc * 8;
    else {
      int half = (ch - 8) >> 1, iv = (ch - 8) & 1;
      dst = Vf + ((((long)bb * 2 + half) * 32 + (il >> 1)) * 4 + 2 * (il & 1) + iv) * 512 + pc * 8;
    }
    *(bf16x8*)dst = val;
  }
}

// ---------------------------------------------------------------------------
// Kernel 2: flash attention — EXACT R5 version (A/B control, single launch).
// ---------------------------------------------------------------------------
__device__ __forceinline__ bf16x8 pack8(float p0, float p1, float p2, float p3,
                                        float p4, float p5, float p6, float p7,
                                        int hi) {
  u32 A = pk2(p0, p1), B = pk2(p2, p3), C = pk2(p4, p5), D = pk2(p6, p7);
  u32 sA = (u32)__shfl_xor((int)A, 32);
  u32 sB = (u32)__shfl_xor((int)B, 32);
  u32 sC = (u32)__shfl_xor((int)C, 32);
  u32 sD = (u32)__shfl_xor((int)D, 32);
  union { u32 w[4]; bf16x8 v; } u;
  u.w[0] = hi ? sC : A;
  u.w[1] = hi ? sD : B;
  u.w[2] = hi ? C : sA;
  u.w[3] = hi ? D : sB;
  return u.v;
}

__global__ __launch_bounds__(512) void attn_kernel(
    const u16* __restrict__ Qf, const u16* __restrict__ Kf,
    const u16* __restrict__ Vf, float* __restrict__ out) {
  __shared__ float Ol[8][32][64];
  __shared__ float Ll[8][32];
  int w = threadIdx.x >> 6, lane = threadIdx.x & 63;
  int q = lane & 31, hi = lane >> 5;
  int bid = blockIdx.x;
  int b = (bid & 7) >> 1;                      // batch b on XCDs {2b,2b+1}
  int qt = ((bid >> 3) << 1) | (bid & 1);
  long qglob = (long)b * NS + qt * 32;

  bf16x8 qf[4];
  {
    const u16* qp = Qf + ((long)b * 64 + qt) * 2048 + lane * 8;
#pragma unroll
    for (int kk = 0; kk < 4; kk++) qf[kk] = *(const bf16x8*)(qp + kk * 512);
  }
  const u16* kcp = Kf + ((long)b * 64 + w * 8) * 2048 + lane * 8;
  const u16* vcp0 = Vf + ((long)b * 64 + w * 4) * 2048 + lane * 8;
  const u16* vcp1 = Vf + ((long)(b * 2 + 1) * 32 + w * 4) * 2048 + lane * 8;

  f32x16 o0, o1;
#pragma unroll
  for (int r = 0; r < 16; r++) { o0[r] = 0.f; o1[r] = 0.f; }
  float lacc[4] = {0.f, 0.f, 0.f, 0.f};

  bf16x8 kA0[4], kA1[4], kB0[4], kB1[4];
#pragma unroll
  for (int kk = 0; kk < 4; kk++) {             // prologue: K frags for t=0
    kA0[kk] = *(const bf16x8*)(kcp + kk * 512);
    kA1[kk] = *(const bf16x8*)(kcp + 2048 + kk * 512);
  }

#define ATTN_STEP(T, KC0, KC1, KN0, KN1)                                      \
  do {                                                                        \
    int t_ = (T);                                                             \
    bf16x8 vf0[4], vf1[4];                                                    \
    _Pragma("unroll") for (int i = 0; i < 4; i++) {                           \
      vf0[i] = *(const bf16x8*)(vcp0 + t_ * 2048 + i * 512);                  \
      vf1[i] = *(const bf16x8*)(vcp1 + t_ * 2048 + i * 512);                  \
    }                                                                         \
    if (t_ + 1 < 4) {                                                         \
      const u16* kn_ = kcp + (long)(t_ + 1) * 4096;                           \
      _Pragma("unroll") for (int i = 0; i < 4; i++) {                         \
        KN0[i] = *(const bf16x8*)(kn_ + i * 512);                             \
        KN1[i] = *(const bf16x8*)(kn_ + 2048 + i * 512);                      \
      }                                                                       \
    }                                                                         \
    __builtin_amdgcn_sched_barrier(0);                                        \
    f32x16 s0, s1;                                                            \
    _Pragma("unroll") for (int r = 0; r < 16; r++) { s0[r] = 0.f; s1[r] = 0.f; } \
    _Pragma("unroll") for (int i = 0; i < 4; i++)                             \
      s0 = __builtin_amdgcn_mfma_f32_32x32x16_bf16(KC0[i], qf[i], s0, 0, 0, 0); \
    _Pragma("unroll") for (int i = 0; i < 4; i++)                             \
      s1 = __builtin_amdgcn_mfma_f32_32x32x16_bf16(KC1[i], qf[i], s1, 0, 0, 0); \
    _Pragma("unroll") for (int r = 0; r < 16; r++) {                          \
      s0[r] = exp2f(s0[r]); s1[r] = exp2f(s1[r]);                             \
      lacc[r & 3] += s0[r] + s1[r];                                           \
    }                                                                         \
    bf16x8 pa[4];                                                             \
    pa[0] = pack8(s0[0], s0[1], s0[2], s0[3], s0[4], s0[5], s0[6], s0[7], hi);   \
    pa[1] = pack8(s0[8], s0[9], s0[10], s0[11], s0[12], s0[13], s0[14], s0[15], hi); \
    pa[2] = pack8(s1[0], s1[1], s1[2], s1[3], s1[4], s1[5], s1[6], s1[7], hi);   \
    pa[3] = pack8(s1[8], s1[9], s1[10], s1[11], s1[12], s1[13], s1[14], s1[15], hi); \
    _Pragma("unroll") for (int i = 0; i < 4; i++) {                           \
      o0 = __builtin_amdgcn_mfma_f32_32x32x16_bf16(pa[i], vf0[i], o0, 0, 0, 0); \
      o1 = __builtin_amdgcn_mfma_f32_32x32x16_bf16(pa[i], vf1[i], o1, 0, 0, 0); \
    }                                                                         \
  } while (0)

  ATTN_STEP(0, kA0, kA1, kB0, kB1);
  ATTN_STEP(1, kB0, kB1, kA0, kA1);
  ATTN_STEP(2, kA0, kA1, kB0, kB1);
  ATTN_STEP(3, kB0, kB1, kA0, kA1);
#undef ATTN_STEP

  float lt = (lacc[0] + lacc[1]) + (lacc[2] + lacc[3]);
  lt += __shfl_xor(lt, 32);

#pragma unroll
  for (int r = 0; r < 16; r++) {
    int qq = (r & 3) + 8 * (r >> 2) + 4 * hi;
    Ol[w][qq][q]      = o0[r];
    Ol[w][qq][q + 32] = o1[r];
  }
  if (hi == 0) Ll[w][q] = lt;
  __syncthreads();

#pragma unroll
  for (int rr = 4; rr >= 1; rr >>= 1) {
    if (w < rr) {
#pragma unroll
      for (int i = 0; i < 8; i++) {
        int idx = lane + i * 64;
        f32x4* dst = (f32x4*)&Ol[w][idx >> 4][(idx & 15) * 4];
        const f32x4* src = (const f32x4*)&Ol[w + rr][idx >> 4][(idx & 15) * 4];
        *dst += *src;
      }
      if (lane < 32) Ll[w][lane] += Ll[w + rr][lane];
    }
    __syncthreads();
  }

  {
    int idx = threadIdx.x;
    int row = idx >> 4, c4 = (idx & 15) * 4;
    float inv = 1.0f / Ll[0][row];
    f32x4 v = *(const f32x4*)&Ol[0][row][c4];
    f32x4 r;
#pragma unroll
    for (int i = 0; i < 4; i++) r[i] = v[i] * inv;
    *(f32x4*)&out[(qglob + row) * NK + c4] = r;
  }
}

// ---------------------------------------------------------------------------
extern "C" void kernel_launch(void* const* d_in, const int* in_sizes, int n_in,
                              void* d_out, int out_size, void* d_ws, size_t ws_size,
                              hipStream_t stream) {
  const float* x  = (const float*)d_in[0];
  const float* Wq = (const float*)d_in[1];
  const float* Bq = (const float*)d_in[2];
  const float* Wk = (const float*)d_in[3];
  const float* Bk = (const float*)d_in[4];
  const float* Wv = (const float*)d_in[5];
  const float* Bv = (const float*)d_in[6];
  float* out = (float*)d_out;

  char* ws = (char*)d_ws;
  u16* Wt = (u16*)ws;                         // 384 KB
  u16* Qf = (u16*)(ws + 393216);              // 1 MB, fragment order
  u16* Kf = (u16*)(ws + 1441792);             // 1 MB, fragment order
  u16* Vf = (u16*)(ws + 2490368);             // 1 MB, fragment order

  wtrans_kernel<<<dim3(48), dim3(256), 0, stream>>>(Wq, Wk, Wv, Wt);
  qkv_kernel<<<dim3(256), dim3(512), 0, stream>>>(x, Wt, Bq, Bk, Bv, Qf, Kf, Vf);
  attn_kernel<<<dim3(256), dim3(512), 0, stream>>>(Qf, Kf, Vf, out);
}